// Round 4
// baseline (152.200 us; speedup 1.0000x reference)
//
#include <hip/hip_runtime.h>

#define NQ_ 30000
#define NC_ 16
#define C_  128
#define NS_ 8192

typedef __attribute__((ext_vector_type(4))) float  f32x4;
typedef __attribute__((ext_vector_type(8))) short  s16x8;

// workspace layout (float offsets)
#define WS_PART  0         // 16 cls * 16 chunks * 128 = 32768
#define WS_PCNT  32768     // 256
#define WS_T     33024     // 2048  (protos @ Wp + b1)
#define WS_PACK  35072     // shorts: W2frag[16384] Wqfrag[16384] pnfrag[2048]

__device__ inline short f2bf(float x){           // round-to-nearest-even bf16
  unsigned u = __float_as_uint(x);
  u += 0x7fffu + ((u >> 16) & 1u);
  return (short)(u >> 16);
}

// ---- prototypes: deterministic fixed-order partial sums ----
__global__ __launch_bounds__(128) void proto_part(const float* __restrict__ sf,
                                                  const int* __restrict__ lbl,
                                                  float* __restrict__ ws){
  const int cls = blockIdx.x >> 4;
  const int ch  = blockIdx.x & 15;
  const int c   = threadIdx.x;
  const int r0  = ch * (NS_/16);
  float s = 0.f; int cnt = 0;
  #pragma unroll 4
  for (int r = r0; r < r0 + NS_/16; ++r){
    if (lbl[r] == cls){ s += sf[(size_t)r*C_ + c]; ++cnt; }
  }
  ws[WS_PART + (cls*16 + ch)*C_ + c] = s;
  if (c == 0) ws[WS_PCNT + cls*16 + ch] = (float)cnt;
}

// ---- fused: finalize protos + pn + tmat + weight pack (one block, 512 thr) ----
__global__ __launch_bounds__(512) void prep2(const float* __restrict__ W1,
                                             const float* __restrict__ b1,
                                             const float* __restrict__ W2,
                                             float* __restrict__ ws){
  __shared__ float p[NC_][C_];
  __shared__ float pn[NC_][C_];
  __shared__ float rn[NC_];
  __shared__ float cl[NC_];
  const int t = threadIdx.x;
  if (t < NC_){
    float s = 0.f;
    #pragma unroll
    for (int ch = 0; ch < 16; ++ch) s += ws[WS_PCNT + t*16 + ch];
    cl[t] = s;
  }
  __syncthreads();
  #pragma unroll
  for (int j = 0; j < 4; ++j){
    const int idx = j*512 + t, n = idx >> 7, c = idx & 127;
    float s = 0.f;
    #pragma unroll
    for (int ch = 0; ch < 16; ++ch) s += ws[WS_PART + (n*16 + ch)*C_ + c];
    const float cv = cl[n];
    p[n][c] = (cv > 0.f) ? s / fmaxf(cv, 1.f) : 0.f;
  }
  __syncthreads();
  if (t < NC_){
    float s = 0.f;
    #pragma unroll 4
    for (int c = 0; c < C_; ++c) s = fmaf(p[t][c], p[t][c], s);
    rn[t] = 1.f / fmaxf(sqrtf(s), 1e-8f);
  }
  __syncthreads();
  #pragma unroll
  for (int j = 0; j < 4; ++j){
    const int idx = j*512 + t, n = idx >> 7, c = idx & 127;
    pn[n][c] = p[n][c] * rn[n];
  }
  // t-matrix: protos @ Wp + b1
  #pragma unroll
  for (int j = 0; j < 4; ++j){
    const int idx = j*512 + t, n = idx >> 7, h = idx & 127;
    float acc = b1[h];
    #pragma unroll 4
    for (int c = 0; c < C_; ++c) acc = fmaf(p[n][c], W1[(C_ + c)*C_ + h], acc);
    ws[WS_T + idx] = acc;
  }
  __syncthreads();   // pn visible for pack
  short* packo = (short*)(ws + WS_PACK);
  for (int g = t; g < 34816; g += 512){
    const int gg = g & 16383, i = gg & 7, ln = (gg >> 3) & 63, ks = (gg >> 9) & 3, wvv = gg >> 11;
    const int k = ks*32 + ((ln >> 4) & 3)*8 + i, col = wvv*16 + (ln & 15);
    float v;
    if (g < 16384)      v = W2[k*C_ + col];
    else if (g < 32768) v = W1[k*C_ + col];     // Wq = W1 rows [0,128)
    else                v = pn[ln & 15][k];     // pn^T B-frags
    packo[g] = f2bf(v);
  }
}

// ---- fused main: 256 thr / 8 queries per block, zero barriers in main loop ----
__global__ __launch_bounds__(256) void fused_main(const float* __restrict__ qfeat,
                                                  const float* __restrict__ W1,
                                                  const float* __restrict__ b2,
                                                  const float* __restrict__ ws,
                                                  float* __restrict__ out){
  __shared__ __align__(16) short w2l[16384];     // 32 KB, read-only after prelude
  __shared__ float qfs[16][132];                 // rows 8..15 uninitialized (D rows discarded)
  __shared__ float qw[8][132];
  __shared__ float cosl[8][NC_];
  __shared__ float rqn[8];

  const int t    = threadIdx.x;
  const int lane = t & 63;
  const int wv   = t >> 6;          // 0..3
  const int fr   = lane & 15;
  const int fg   = lane >> 4;
  const int qbase = blockIdx.x * 8;
  const short* pack = (const short*)(ws + WS_PACK);
  float* out_cos = out + (size_t)NQ_ * NC_ * C_;

  // hoist per-lane constants early (latency overlaps staging)
  f32x4 tA[4], tB[4], wA[4], wB[4];
  #pragma unroll
  for (int ks = 0; ks < 4; ++ks){
    const int k0 = ks*32 + fg*8;
    tA[ks] = *(const f32x4*)(ws + WS_T + fr*C_ + k0);
    tB[ks] = *(const f32x4*)(ws + WS_T + fr*C_ + k0 + 4);
    wA[ks] = *(const f32x4*)(W1 + 2*C_*C_ + k0);
    wB[ks] = *(const f32x4*)(W1 + 2*C_*C_ + k0 + 4);
  }
  float b2v[8];
  #pragma unroll
  for (int tt = 0; tt < 8; ++tt) b2v[tt] = b2[tt*16 + fr];

  // stage W2 frags -> LDS (coalesced linear copy)
  {
    const int o = t * 8;  // shorts
    #pragma unroll
    for (int j = 0; j < 8; ++j)
      *(s16x8*)&w2l[j*2048 + o] = *(const s16x8*)&pack[j*2048 + o];
  }
  // stage qf 8x128
  {
    const int idx = t * 4, q = idx >> 7, c = idx & 127;
    *(f32x4*)&qfs[q][c] = *(const f32x4*)(qfeat + (size_t)qbase*C_ + idx);
  }
  __syncthreads();

  // 1/max(||q||,eps) for 8 queries (wave 0)
  if (t < 64){
    const int q = t >> 3, c0 = (t & 7) * 16;
    float s = 0.f;
    #pragma unroll
    for (int m = 0; m < 16; ++m){ float v = qfs[q][c0+m]; s = fmaf(v, v, s); }
    s += __shfl_xor(s, 1); s += __shfl_xor(s, 2); s += __shfl_xor(s, 4);
    if ((t & 7) == 0) rqn[q] = 1.f / fmaxf(sqrtf(s), 1e-8f);
  }

  // A-fragments of qf (rows 8-15 garbage -> D rows 8-15 discarded)
  s16x8 qfr[4];
  #pragma unroll
  for (int ks = 0; ks < 4; ++ks){
    const int c0 = ks*32 + fg*8;
    f32x4 a = *(const f32x4*)&qfs[fr][c0];
    f32x4 b = *(const f32x4*)&qfs[fr][c0+4];
    s16x8 v;
    v[0]=f2bf(a[0]); v[1]=f2bf(a[1]); v[2]=f2bf(a[2]); v[3]=f2bf(a[3]);
    v[4]=f2bf(b[0]); v[5]=f2bf(b[1]); v[6]=f2bf(b[2]); v[7]=f2bf(b[3]);
    qfr[ks] = v;
  }
  __syncthreads();   // qfs reads done; rqn ready

  // qW = qf @ Wq : wave wv covers col-tiles wv and wv+4
  #pragma unroll
  for (int tt0 = 0; tt0 < 2; ++tt0){
    const int tt = wv + tt0*4;
    f32x4 d = {0.f,0.f,0.f,0.f};
    #pragma unroll
    for (int ks = 0; ks < 4; ++ks)
      d = __builtin_amdgcn_mfma_f32_16x16x32_bf16(qfr[ks],
            *(const s16x8*)&pack[16384 + ((tt*4 + ks)*64 + lane)*8], d, 0,0,0);
    if (fg < 2){
      #pragma unroll
      for (int r = 0; r < 4; ++r) qw[fg*4 + r][tt*16 + fr] = d[r];
    }
  }
  // cos = (qf @ pn^T) * rqn  (wave 0)
  if (wv == 0){
    f32x4 d = {0.f,0.f,0.f,0.f};
    #pragma unroll
    for (int ks = 0; ks < 4; ++ks)
      d = __builtin_amdgcn_mfma_f32_16x16x32_bf16(qfr[ks],
            *(const s16x8*)&pack[32768 + (ks*64 + lane)*8], d, 0,0,0);
    if (fg < 2){
      #pragma unroll
      for (int r = 0; r < 4; ++r){
        const int q = fg*4 + r;
        const float cv = d[r] * rqn[q];
        cosl[q][fr] = cv;
        out_cos[(size_t)(qbase + q)*NC_ + fr] = cv;
      }
    }
  }
  __syncthreads();   // qw, cosl ready — LAST barrier

  // main loop: wave owns queries wv*2, wv*2+1. No barriers, stores never drained.
  #pragma unroll
  for (int qq = 0; qq < 2; ++qq){
    const int q = wv*2 + qq;
    const float cv = cosl[q][fr];
    // A-fragments of H in registers: H[n=fr][k] = relu(qw+t+cv*wc)
    s16x8 af[4];
    #pragma unroll
    for (int ks = 0; ks < 4; ++ks){
      const int k0 = ks*32 + fg*8;
      f32x4 qa = *(const f32x4*)&qw[q][k0];      // broadcast, conflict-free
      f32x4 qb = *(const f32x4*)&qw[q][k0+4];
      s16x8 v;
      #pragma unroll
      for (int j = 0; j < 4; ++j){
        float h = fmaf(cv, wA[ks][j], qa[j] + tA[ks][j]);
        v[j] = f2bf(fmaxf(h, 0.f));
      }
      #pragma unroll
      for (int j = 0; j < 4; ++j){
        float h = fmaf(cv, wB[ks][j], qb[j] + tB[ks][j]);
        v[4+j] = f2bf(fmaxf(h, 0.f));
      }
      af[ks] = v;
    }
    const size_t qo = (size_t)(qbase + q) * (NC_*C_);
    #pragma unroll
    for (int tt = 0; tt < 8; ++tt){
      f32x4 acc = {b2v[tt], b2v[tt], b2v[tt], b2v[tt]};
      #pragma unroll
      for (int ks = 0; ks < 4; ++ks)
        acc = __builtin_amdgcn_mfma_f32_16x16x32_bf16(af[ks],
                *(const s16x8*)&w2l[((tt*4 + ks)*64 + lane)*8], acc, 0,0,0);
      #pragma unroll
      for (int r = 0; r < 4; ++r)
        out[qo + (fg*4 + r)*C_ + tt*16 + fr] = acc[r];
    }
  }
}

extern "C" void kernel_launch(void* const* d_in, const int* in_sizes, int n_in,
                              void* d_out, int out_size, void* d_ws, size_t ws_size,
                              hipStream_t stream){
  const float* sf  = (const float*)d_in[0];
  const int*   lbl = (const int*)  d_in[1];
  const float* qf  = (const float*)d_in[2];
  const float* W1  = (const float*)d_in[3];
  const float* b1  = (const float*)d_in[4];
  const float* W2  = (const float*)d_in[5];
  const float* b2  = (const float*)d_in[6];
  float* ws  = (float*)d_ws;
  float* out = (float*)d_out;

  proto_part<<<256, 128, 0, stream>>>(sf, lbl, ws);
  prep2<<<1, 512, 0, stream>>>(W1, b1, W2, ws);
  fused_main<<<NQ_/8, 256, 0, stream>>>(qf, W1, b2, ws, out);
}

// Round 5
// 128.215 us; speedup vs baseline: 1.1871x; 1.1871x over previous
//
#include <hip/hip_runtime.h>

#define NQ_ 30000
#define NC_ 16
#define C_  128
#define NS_ 8192
#define QB  16
#define NBLK (NQ_/QB)   // 1875

typedef __attribute__((ext_vector_type(4))) float  f32x4;
typedef __attribute__((ext_vector_type(4))) short  s16x4;
typedef __attribute__((ext_vector_type(8))) short  s16x8;

// workspace layout (float offsets)
#define WS_PART  0         // 16 cls * 16 chunks * 128 = 32768
#define WS_PCNT  32768     // 256
#define WS_T     33024     // 2048  (protos @ Wp + b1)
#define WS_PACK  35072     // shorts: W2frag[16384] Wqfrag[16384] pnfrag[2048]

// LDS-only barrier: does NOT drain vmcnt -> global stores stay in flight
#define BAR_LGKM() asm volatile("s_waitcnt lgkmcnt(0)\ns_barrier" ::: "memory")

__device__ inline short f2bf(float x){           // round-to-nearest-even bf16
  unsigned u = __float_as_uint(x);
  u += 0x7fffu + ((u >> 16) & 1u);
  return (short)(u >> 16);
}

// ---- prototypes: deterministic fixed-order partial sums ----
__global__ __launch_bounds__(128) void proto_part(const float* __restrict__ sf,
                                                  const int* __restrict__ lbl,
                                                  float* __restrict__ ws){
  const int cls = blockIdx.x >> 4;
  const int ch  = blockIdx.x & 15;
  const int c   = threadIdx.x;
  const int r0  = ch * (NS_/16);
  float s = 0.f; int cnt = 0;
  #pragma unroll 4
  for (int r = r0; r < r0 + NS_/16; ++r){
    if (lbl[r] == cls){ s += sf[(size_t)r*C_ + c]; ++cnt; }
  }
  ws[WS_PART + (cls*16 + ch)*C_ + c] = s;
  if (c == 0) ws[WS_PCNT + cls*16 + ch] = (float)cnt;
}

// ---- fused: finalize protos + pn + tmat + weight pack (one block, 512 thr) ----
__global__ __launch_bounds__(512) void prep2(const float* __restrict__ W1,
                                             const float* __restrict__ b1,
                                             const float* __restrict__ W2,
                                             float* __restrict__ ws){
  __shared__ float p[NC_][C_];
  __shared__ float pn[NC_][C_];
  __shared__ float rn[NC_];
  __shared__ float cl[NC_];
  const int t = threadIdx.x;
  if (t < NC_){
    float s = 0.f;
    #pragma unroll
    for (int ch = 0; ch < 16; ++ch) s += ws[WS_PCNT + t*16 + ch];
    cl[t] = s;
  }
  __syncthreads();
  #pragma unroll
  for (int j = 0; j < 4; ++j){
    const int idx = j*512 + t, n = idx >> 7, c = idx & 127;
    float s = 0.f;
    #pragma unroll
    for (int ch = 0; ch < 16; ++ch) s += ws[WS_PART + (n*16 + ch)*C_ + c];
    const float cv = cl[n];
    p[n][c] = (cv > 0.f) ? s / fmaxf(cv, 1.f) : 0.f;
  }
  __syncthreads();
  if (t < NC_){
    float s = 0.f;
    #pragma unroll 4
    for (int c = 0; c < C_; ++c) s = fmaf(p[t][c], p[t][c], s);
    rn[t] = 1.f / fmaxf(sqrtf(s), 1e-8f);
  }
  __syncthreads();
  #pragma unroll
  for (int j = 0; j < 4; ++j){
    const int idx = j*512 + t, n = idx >> 7, c = idx & 127;
    pn[n][c] = p[n][c] * rn[n];
  }
  // t-matrix: protos @ Wp + b1
  #pragma unroll
  for (int j = 0; j < 4; ++j){
    const int idx = j*512 + t, n = idx >> 7, h = idx & 127;
    float acc = b1[h];
    #pragma unroll 4
    for (int c = 0; c < C_; ++c) acc = fmaf(p[n][c], W1[(C_ + c)*C_ + h], acc);
    ws[WS_T + idx] = acc;
  }
  __syncthreads();   // pn visible for pack
  short* packo = (short*)(ws + WS_PACK);
  for (int g = t; g < 34816; g += 512){
    const int gg = g & 16383, i = gg & 7, ln = (gg >> 3) & 63, ks = (gg >> 9) & 3, wvv = gg >> 11;
    const int k = ks*32 + ((ln >> 4) & 3)*8 + i, col = wvv*16 + (ln & 15);
    float v;
    if (g < 16384)      v = W2[k*C_ + col];
    else if (g < 32768) v = W1[k*C_ + col];     // Wq = W1 rows [0,128)
    else                v = pn[ln & 15][k];     // pn^T B-frags
    packo[g] = f2bf(v);
  }
}

// ---- fused main: exact R2 structure, only barrier type changed ----
__global__ __launch_bounds__(512) void fused_main(const float* __restrict__ qfeat,
                                                  const float* __restrict__ W1,
                                                  const float* __restrict__ b2,
                                                  const float* __restrict__ ws,
                                                  float* __restrict__ out){
  __shared__ __align__(16) char un[16384];   // qfs[16][132] f32, then hfrag[4*2048] bf16
  __shared__ float qw[QB][132];
  __shared__ float tl16[NC_][132];
  __shared__ float cosl[QB][NC_];
  __shared__ float rqn[QB];
  __shared__ float wcl[C_];

  float (*qfs)[132] = (float(*)[132])un;
  short* hfrag = (short*)un;

  const int t    = threadIdx.x;
  const int lane = t & 63;
  const int wv   = t >> 6;
  const int qbase = blockIdx.x * QB;
  float* out_cos = out + (size_t)NQ_ * NC_ * C_;
  const short* pack = (const short*)(ws + WS_PACK);

  // stage qf (16x128), t-matrix, Wc — all coalesced
  {
    int idx = t * 4; int q = idx >> 7; int c = idx & 127;
    *(f32x4*)&qfs[q][c]  = *(const f32x4*)(qfeat + (size_t)qbase*C_ + idx);
    *(f32x4*)&tl16[q][c] = *(const f32x4*)(ws + WS_T + idx);
    if (t < 32) *(f32x4*)&wcl[t*4] = *(const f32x4*)(W1 + 2*C_*C_ + t*4);
  }
  BAR_LGKM();

  // 1/max(||q||, eps)
  if (t < 128){
    int q = t >> 3; int c0 = (t & 7) * 16;
    float s = 0.f;
    #pragma unroll
    for (int m = 0; m < 16; ++m){ float v = qfs[q][c0+m]; s = fmaf(v, v, s); }
    s += __shfl_xor(s, 1); s += __shfl_xor(s, 2); s += __shfl_xor(s, 4);
    if ((t & 7) == 0) rqn[q] = 1.f / fmaxf(sqrtf(s), 1e-8f);
  }

  const int fr = lane & 15;
  const int fg = lane >> 4;
  const int ocol = wv*16 + fr;

  // A-fragments of qf; B-fragments of W2/Wq coalesced from pack
  s16x8 qfr[4], w2f[4], wqf[4];
  #pragma unroll
  for (int ks = 0; ks < 4; ++ks){
    const int c0 = ks*32 + fg*8;
    f32x4 a = *(const f32x4*)&qfs[fr][c0];
    f32x4 b = *(const f32x4*)&qfs[fr][c0+4];
    s16x8 v;
    v[0]=f2bf(a[0]); v[1]=f2bf(a[1]); v[2]=f2bf(a[2]); v[3]=f2bf(a[3]);
    v[4]=f2bf(b[0]); v[5]=f2bf(b[1]); v[6]=f2bf(b[2]); v[7]=f2bf(b[3]);
    qfr[ks] = v;
    w2f[ks] = *(const s16x8*)&pack[((wv*4 + ks)*64 + lane)*8];
    wqf[ks] = *(const s16x8*)&pack[16384 + ((wv*4 + ks)*64 + lane)*8];
  }
  const float b2v = b2[ocol];
  BAR_LGKM();        // rqn ready; all qfs reads done

  // qW = qf @ Wq
  {
    f32x4 dq = {0.f,0.f,0.f,0.f};
    #pragma unroll
    for (int ks = 0; ks < 4; ++ks)
      dq = __builtin_amdgcn_mfma_f32_16x16x32_bf16(qfr[ks], wqf[ks], dq, 0,0,0);
    #pragma unroll
    for (int r = 0; r < 4; ++r) qw[fg*4 + r][ocol] = dq[r];
  }
  // cos = (qf @ pn^T) * rqn   (wave 0)
  if (wv == 0){
    s16x8 pnf[4];
    #pragma unroll
    for (int ks = 0; ks < 4; ++ks)
      pnf[ks] = *(const s16x8*)&pack[32768 + (ks*64 + lane)*8];
    f32x4 dc = {0.f,0.f,0.f,0.f};
    #pragma unroll
    for (int ks = 0; ks < 4; ++ks)
      dc = __builtin_amdgcn_mfma_f32_16x16x32_bf16(qfr[ks], pnf[ks], dc, 0,0,0);
    #pragma unroll
    for (int r = 0; r < 4; ++r){
      const int q = fg*4 + r;
      const float cv = dc[r] * rqn[q];
      cosl[q][fr] = cv;
      out_cos[(size_t)(qbase + q)*NC_ + fr] = cv;
    }
  }
  BAR_LGKM();        // qw, cosl ready; qfs dead -> hfrag live

  // phase-A constants: wave wv handles (ksA, ii0); lane -> (class na, k-group ga)
  const int na  = lane & 15;
  const int ga  = lane >> 4;
  const int ksA = wv >> 1;
  const int ii0 = (wv & 1) * 4;
  const int k0  = ksA*32 + ga*8 + ii0;
  const f32x4 t4  = *(const f32x4*)&tl16[na][k0];
  const f32x4 wc4 = *(const f32x4*)&wcl[k0];

  #pragma unroll
  for (int chunk = 0; chunk < 4; ++chunk){
    const int q0 = chunk * 4;
    // phase A: H = relu(qW + t_n + cos*Wc) -> bf16 fragments in LDS
    #pragma unroll
    for (int qq = 0; qq < 4; ++qq){
      const int q = q0 + qq;
      f32x4 qw4 = *(const f32x4*)&qw[q][k0];
      const float cv = cosl[q][na];
      s16x4 hv;
      #pragma unroll
      for (int j = 0; j < 4; ++j){
        float h = fmaf(cv, wc4[j], qw4[j] + t4[j]);
        hv[j] = f2bf(fmaxf(h, 0.f));
      }
      *(s16x4*)&hfrag[qq*2048 + ksA*512 + lane*8 + ii0] = hv;
    }
    BAR_LGKM();   // LDS-only: out stores from previous phase B stay in flight
    // phase B: sim = H @ W2 + b2
    #pragma unroll
    for (int qq = 0; qq < 4; ++qq){
      s16x8 a0 = *(const s16x8*)&hfrag[qq*2048 +    0 + lane*8];
      s16x8 a1 = *(const s16x8*)&hfrag[qq*2048 +  512 + lane*8];
      s16x8 a2 = *(const s16x8*)&hfrag[qq*2048 + 1024 + lane*8];
      s16x8 a3 = *(const s16x8*)&hfrag[qq*2048 + 1536 + lane*8];
      f32x4 acc = {b2v, b2v, b2v, b2v};
      acc = __builtin_amdgcn_mfma_f32_16x16x32_bf16(a0, w2f[0], acc, 0,0,0);
      acc = __builtin_amdgcn_mfma_f32_16x16x32_bf16(a1, w2f[1], acc, 0,0,0);
      acc = __builtin_amdgcn_mfma_f32_16x16x32_bf16(a2, w2f[2], acc, 0,0,0);
      acc = __builtin_amdgcn_mfma_f32_16x16x32_bf16(a3, w2f[3], acc, 0,0,0);
      const size_t qout = (size_t)(qbase + q0 + qq) * (NC_*C_);
      #pragma unroll
      for (int r = 0; r < 4; ++r)
        out[qout + (fg*4 + r)*C_ + ocol] = acc[r];
    }
    if (chunk < 3) BAR_LGKM();   // WAR: next A overwrites hfrag after all reads done
  }
}

extern "C" void kernel_launch(void* const* d_in, const int* in_sizes, int n_in,
                              void* d_out, int out_size, void* d_ws, size_t ws_size,
                              hipStream_t stream){
  const float* sf  = (const float*)d_in[0];
  const int*   lbl = (const int*)  d_in[1];
  const float* qf  = (const float*)d_in[2];
  const float* W1  = (const float*)d_in[3];
  const float* b1  = (const float*)d_in[4];
  const float* W2  = (const float*)d_in[5];
  const float* b2  = (const float*)d_in[6];
  float* ws  = (float*)d_ws;
  float* out = (float*)d_out;

  proto_part<<<256, 128, 0, stream>>>(sf, lbl, ws);
  prep2<<<1, 512, 0, stream>>>(W1, b1, W2, ws);
  fused_main<<<NBLK, 512, 0, stream>>>(qf, W1, b2, ws, out);
}

// Round 6
// 89.375 us; speedup vs baseline: 1.7029x; 1.4346x over previous
//
#include <hip/hip_runtime.h>

#define NQ_ 30000
#define NC_ 16
#define C_  128
#define NS_ 8192
#define QB  16
#define NBLK (NQ_/QB)   // 1875

typedef __attribute__((ext_vector_type(4))) float  f32x4;
typedef __attribute__((ext_vector_type(4))) short  s16x4;
typedef __attribute__((ext_vector_type(8))) short  s16x8;

// workspace layout (float offsets)
#define WS_PART  0         // 16 cls * 16 chunks * 128 = 32768
#define WS_PCNT  32768     // 256
#define WS_T     33024     // 2048  (protos @ Wp + b1)
#define WS_PACK  35072     // shorts: W2frag[16384] Wqfrag[16384] pnfrag[2048]

__device__ inline short f2bf(float x){           // round-to-nearest-even bf16
  unsigned u = __float_as_uint(x);
  u += 0x7fffu + ((u >> 16) & 1u);
  return (short)(u >> 16);
}

// ---- kernel A: proto partial sums (blocks 0..255) + W2/Wq pack (blocks 256..287) ----
__global__ __launch_bounds__(128) void protoA(const float* __restrict__ sf,
                                              const int* __restrict__ lbl,
                                              const float* __restrict__ W1,
                                              const float* __restrict__ W2,
                                              float* __restrict__ ws){
  const int b = blockIdx.x;
  const int t = threadIdx.x;
  if (b < 256){
    const int cls = b >> 4;
    const int ch  = b & 15;
    const int r0  = ch * (NS_/16);
    float s = 0.f; int cnt = 0;
    #pragma unroll 4
    for (int r = r0; r < r0 + NS_/16; ++r){
      if (lbl[r] == cls){ s += sf[(size_t)r*C_ + t]; ++cnt; }
    }
    ws[WS_PART + (cls*16 + ch)*C_ + t] = s;
    if (t == 0) ws[WS_PCNT + cls*16 + ch] = (float)cnt;
  } else {
    // pack W2 (g<16384) / Wq (g>=16384) into MFMA B-fragment order
    short* packo = (short*)(ws + WS_PACK);
    const int g0 = (b - 256)*1024 + t*8;
    const int gg = g0 & 16383;
    const int ln = (gg >> 3) & 63, ks = (gg >> 9) & 3, wvv = gg >> 11;
    const int kb = ks*32 + ((ln >> 4) & 3)*8;
    const int col = wvv*16 + (ln & 15);
    const float* src = (g0 < 16384) ? W2 : W1;    // Wq = W1 rows [0,128)
    s16x8 v;
    #pragma unroll
    for (int i = 0; i < 8; ++i) v[i] = f2bf(src[(size_t)(kb + i)*C_ + col]);
    *(s16x8*)&packo[g0] = v;
  }
}

// ---- kernel B: per-class finalize + pn + tmat + pn-pack (16 blocks x 128 thr) ----
__global__ __launch_bounds__(128) void protoB(const float* __restrict__ W1,
                                              const float* __restrict__ b1,
                                              float* __restrict__ ws){
  __shared__ float pr[C_];
  __shared__ float rns;
  const int n = blockIdx.x;
  const int h = threadIdx.x;
  float s = 0.f;
  #pragma unroll
  for (int ch = 0; ch < 16; ++ch) s += ws[WS_PART + (n*16 + ch)*C_ + h];
  float cnt = 0.f;
  #pragma unroll
  for (int ch = 0; ch < 16; ++ch) cnt += ws[WS_PCNT + n*16 + ch];
  const float pv = (cnt > 0.f) ? s / fmaxf(cnt, 1.f) : 0.f;
  pr[h] = pv;
  __syncthreads();
  if (h < 64){
    float q = pr[h]*pr[h] + pr[h+64]*pr[h+64];
    q += __shfl_xor(q, 1);  q += __shfl_xor(q, 2);  q += __shfl_xor(q, 4);
    q += __shfl_xor(q, 8);  q += __shfl_xor(q, 16); q += __shfl_xor(q, 32);
    if (h == 0) rns = 1.f / fmaxf(sqrtf(q), 1e-8f);
  }
  __syncthreads();
  // pn-pack: thread h handles k=h for class n
  {
    short* packo = (short*)(ws + WS_PACK);
    const int k = h;
    const int gg = ((k >> 5)*64 + ((k >> 3) & 3)*16 + n)*8 + (k & 7);
    packo[32768 + gg] = f2bf(pv * rns);
  }
  // tmat: ws[WS_T + n*C_ + h] = b1[h] + sum_c pr[c]*W1[(C+c)*C+h]
  float acc = b1[h];
  #pragma unroll 8
  for (int c = 0; c < C_; ++c) acc = fmaf(pr[c], W1[(size_t)(C_ + c)*C_ + h], acc);
  ws[WS_T + n*C_ + h] = acc;
}

// ---- fused main: byte-identical to the R2 (104.5 us) version ----
__global__ __launch_bounds__(512) void fused_main(const float* __restrict__ qfeat,
                                                  const float* __restrict__ W1,
                                                  const float* __restrict__ b2,
                                                  const float* __restrict__ ws,
                                                  float* __restrict__ out){
  __shared__ __align__(16) char un[16384];   // qfs[16][132] f32, then hfrag[4*2048] bf16
  __shared__ float qw[QB][132];
  __shared__ float tl16[NC_][132];
  __shared__ float cosl[QB][NC_];
  __shared__ float rqn[QB];
  __shared__ float wcl[C_];

  float (*qfs)[132] = (float(*)[132])un;
  short* hfrag = (short*)un;

  const int t    = threadIdx.x;
  const int lane = t & 63;
  const int wv   = t >> 6;
  const int qbase = blockIdx.x * QB;
  float* out_cos = out + (size_t)NQ_ * NC_ * C_;
  const short* pack = (const short*)(ws + WS_PACK);

  // stage qf (16x128), t-matrix, Wc — all coalesced
  {
    int idx = t * 4; int q = idx >> 7; int c = idx & 127;
    *(f32x4*)&qfs[q][c]  = *(const f32x4*)(qfeat + (size_t)qbase*C_ + idx);
    *(f32x4*)&tl16[q][c] = *(const f32x4*)(ws + WS_T + idx);
    if (t < 32) *(f32x4*)&wcl[t*4] = *(const f32x4*)(W1 + 2*C_*C_ + t*4);
  }
  __syncthreads();

  // 1/max(||q||, eps)
  if (t < 128){
    int q = t >> 3; int c0 = (t & 7) * 16;
    float s = 0.f;
    #pragma unroll
    for (int m = 0; m < 16; ++m){ float v = qfs[q][c0+m]; s = fmaf(v, v, s); }
    s += __shfl_xor(s, 1); s += __shfl_xor(s, 2); s += __shfl_xor(s, 4);
    if ((t & 7) == 0) rqn[q] = 1.f / fmaxf(sqrtf(s), 1e-8f);
  }

  const int fr = lane & 15;
  const int fg = lane >> 4;
  const int ocol = wv*16 + fr;

  // A-fragments of qf; B-fragments of W2/Wq coalesced from pack
  s16x8 qfr[4], w2f[4], wqf[4];
  #pragma unroll
  for (int ks = 0; ks < 4; ++ks){
    const int c0 = ks*32 + fg*8;
    f32x4 a = *(const f32x4*)&qfs[fr][c0];
    f32x4 b = *(const f32x4*)&qfs[fr][c0+4];
    s16x8 v;
    v[0]=f2bf(a[0]); v[1]=f2bf(a[1]); v[2]=f2bf(a[2]); v[3]=f2bf(a[3]);
    v[4]=f2bf(b[0]); v[5]=f2bf(b[1]); v[6]=f2bf(b[2]); v[7]=f2bf(b[3]);
    qfr[ks] = v;
    w2f[ks] = *(const s16x8*)&pack[((wv*4 + ks)*64 + lane)*8];
    wqf[ks] = *(const s16x8*)&pack[16384 + ((wv*4 + ks)*64 + lane)*8];
  }
  const float b2v = b2[ocol];
  __syncthreads();   // rqn ready; all qfs reads done

  // qW = qf @ Wq
  {
    f32x4 dq = {0.f,0.f,0.f,0.f};
    #pragma unroll
    for (int ks = 0; ks < 4; ++ks)
      dq = __builtin_amdgcn_mfma_f32_16x16x32_bf16(qfr[ks], wqf[ks], dq, 0,0,0);
    #pragma unroll
    for (int r = 0; r < 4; ++r) qw[fg*4 + r][ocol] = dq[r];
  }
  // cos = (qf @ pn^T) * rqn   (wave 0)
  if (wv == 0){
    s16x8 pnf[4];
    #pragma unroll
    for (int ks = 0; ks < 4; ++ks)
      pnf[ks] = *(const s16x8*)&pack[32768 + (ks*64 + lane)*8];
    f32x4 dc = {0.f,0.f,0.f,0.f};
    #pragma unroll
    for (int ks = 0; ks < 4; ++ks)
      dc = __builtin_amdgcn_mfma_f32_16x16x32_bf16(qfr[ks], pnf[ks], dc, 0,0,0);
    #pragma unroll
    for (int r = 0; r < 4; ++r){
      const int q = fg*4 + r;
      const float cv = dc[r] * rqn[q];
      cosl[q][fr] = cv;
      out_cos[(size_t)(qbase + q)*NC_ + fr] = cv;
    }
  }
  __syncthreads();   // qw, cosl ready; qfs dead -> hfrag live

  // phase-A constants: wave wv handles (ksA, ii0); lane -> (class na, k-group ga)
  const int na  = lane & 15;
  const int ga  = lane >> 4;
  const int ksA = wv >> 1;
  const int ii0 = (wv & 1) * 4;
  const int k0  = ksA*32 + ga*8 + ii0;
  const f32x4 t4  = *(const f32x4*)&tl16[na][k0];
  const f32x4 wc4 = *(const f32x4*)&wcl[k0];

  #pragma unroll
  for (int chunk = 0; chunk < 4; ++chunk){
    const int q0 = chunk * 4;
    // phase A: H = relu(qW + t_n + cos*Wc) -> bf16 fragments in LDS
    #pragma unroll
    for (int qq = 0; qq < 4; ++qq){
      const int q = q0 + qq;
      f32x4 qw4 = *(const f32x4*)&qw[q][k0];
      const float cv = cosl[q][na];
      s16x4 hv;
      #pragma unroll
      for (int j = 0; j < 4; ++j){
        float h = fmaf(cv, wc4[j], qw4[j] + t4[j]);
        hv[j] = f2bf(fmaxf(h, 0.f));
      }
      *(s16x4*)&hfrag[qq*2048 + ksA*512 + lane*8 + ii0] = hv;
    }
    __syncthreads();
    // phase B: sim = H @ W2 + b2
    #pragma unroll
    for (int qq = 0; qq < 4; ++qq){
      s16x8 a0 = *(const s16x8*)&hfrag[qq*2048 +    0 + lane*8];
      s16x8 a1 = *(const s16x8*)&hfrag[qq*2048 +  512 + lane*8];
      s16x8 a2 = *(const s16x8*)&hfrag[qq*2048 + 1024 + lane*8];
      s16x8 a3 = *(const s16x8*)&hfrag[qq*2048 + 1536 + lane*8];
      f32x4 acc = {b2v, b2v, b2v, b2v};
      acc = __builtin_amdgcn_mfma_f32_16x16x32_bf16(a0, w2f[0], acc, 0,0,0);
      acc = __builtin_amdgcn_mfma_f32_16x16x32_bf16(a1, w2f[1], acc, 0,0,0);
      acc = __builtin_amdgcn_mfma_f32_16x16x32_bf16(a2, w2f[2], acc, 0,0,0);
      acc = __builtin_amdgcn_mfma_f32_16x16x32_bf16(a3, w2f[3], acc, 0,0,0);
      const size_t qout = (size_t)(qbase + q0 + qq) * (NC_*C_);
      #pragma unroll
      for (int r = 0; r < 4; ++r)
        out[qout + (fg*4 + r)*C_ + ocol] = acc[r];
    }
    __syncthreads();
  }
}

extern "C" void kernel_launch(void* const* d_in, const int* in_sizes, int n_in,
                              void* d_out, int out_size, void* d_ws, size_t ws_size,
                              hipStream_t stream){
  const float* sf  = (const float*)d_in[0];
  const int*   lbl = (const int*)  d_in[1];
  const float* qf  = (const float*)d_in[2];
  const float* W1  = (const float*)d_in[3];
  const float* b1  = (const float*)d_in[4];
  const float* W2  = (const float*)d_in[5];
  const float* b2  = (const float*)d_in[6];
  float* ws  = (float*)d_ws;
  float* out = (float*)d_out;

  protoA<<<288, 128, 0, stream>>>(sf, lbl, W1, W2, ws);
  protoB<<<NC_, 128, 0, stream>>>(W1, b1, ws);
  fused_main<<<NBLK, 512, 0, stream>>>(qf, W1, b2, ws, out);
}